// Round 2
// baseline (35105.652 us; speedup 1.0000x reference)
//
#include <hip/hip_runtime.h>
#include <cstdint>

typedef unsigned short u16;
typedef unsigned u32;
typedef unsigned long long u64;
typedef __attribute__((ext_vector_type(8))) short bf16x8;
typedef __attribute__((ext_vector_type(4))) float f32x4;

#define S_LEN 1000
#define NWG   32               // scan workgroups (each owns 16 H-columns)

// ---------------- ws layout (bytes) ----------------
// Footprint is kept strictly within the previously-verified bound (68,134,912 B):
// the tagged exchange buffers alias the wcat region, which is dead after gemm_bt<2>.
#define OFF_HALL   0ull                         // (1001*64, 512) bf16 hidden states; xb aliases here (dead before scan)
#define SZ_HALL    (1001ull*64*512*2)
#define OFF_WCAT   (OFF_HALL + SZ_HALL)         // (1536, 448) bf16  [Wh;Wz;Wr] K-padded (dead after proj GEMM)
#define SZ_WCAT    (1536ull*448*2)
#define OFF_HX     (OFF_WCAT)                   // [2][64][512] u32 tagged h exchange (tag16|bf16) — aliases wcat
#define SZ_HX      (2ull*64*512*4)
#define OFF_RHX    (OFF_HX + SZ_HX)             // [2][64][512] u32 tagged r*h exchange — aliases wcat
#define SZ_RHX     (2ull*64*512*4)
#define OFF_WFB    (OFF_WCAT + SZ_WCAT)         // (1024, 512) bf16  Wf row-padded
#define SZ_WFB     (1024ull*512*2)
#define OFF_GSUM   (OFF_WFB + SZ_WFB)
#define OFF_GSQ    (OFF_GSUM + 1536*4)
#define OFF_AALL   (OFF_GSQ  + 1536*4)
#define OFF_CALL   (OFF_AALL + 1536*4)
#define OFF_SSUM   (OFF_CALL + 1536*4)
#define OFF_SSQ    (OFF_SSUM + 1024*4)
#define OFF_AF     (OFF_SSQ  + 1024*4)
#define OFF_CF     (OFF_AF   + 1024*4)
#define STATS_ZERO_BYTES (OFF_CF + 1024*4 - OFF_SSUM)

#define TAGMASK 0xFFFF0000FFFF0000ull

// ---------------- helpers ----------------
__device__ __forceinline__ float bf2f(u16 u) {
  union { unsigned u; float f; } v; v.u = ((unsigned)u) << 16; return v.f;
}
__device__ __forceinline__ u16 f2bf(float f) {   // RNE
  union { float f; unsigned u; } v; v.f = f;
  unsigned r = (v.u + 0x7fffu + ((v.u >> 16) & 1u)) >> 16;
  return (u16)r;
}
__device__ __forceinline__ float sigm(float x) { return 1.f / (1.f + __expf(-x)); }
__device__ __forceinline__ float tanh_(float x) {
  float e = __expf(-2.f * fabsf(x));
  float r = (1.f - e) / (1.f + e);
  return x >= 0.f ? r : -r;
}

// LLC-coherent (device-scope, no-fence) exchange primitives: lower to sc0 sc1 ops
__device__ __forceinline__ u64 ld8(const u32* p) {
  return __hip_atomic_load((const u64*)p, __ATOMIC_RELAXED, __HIP_MEMORY_SCOPE_AGENT);
}
__device__ __forceinline__ void st4(u32* p, u32 v) {
  __hip_atomic_store(p, v, __ATOMIC_RELAXED, __HIP_MEMORY_SCOPE_AGENT);
}

// async global->LDS, 16B/lane
__device__ __forceinline__ void stage16(const u16* g, u16* l) {
  __builtin_amdgcn_global_load_lds((const __attribute__((address_space(1))) unsigned int*)(g),
                                   (__attribute__((address_space(3))) unsigned int*)(l), 16, 0, 0);
}

// ---------------- fp32 -> bf16 converts with padding ----------------
__global__ void cvt_pad(const float* __restrict__ src, u16* __restrict__ dst, int incols, int outcols) {
  int r = blockIdx.x, ci = threadIdx.x;
  float v = (ci < incols) ? src[(size_t)r * incols + ci] : 0.f;
  dst[(size_t)r * outcols + ci] = f2bf(v);
}
__global__ void cvt_wf(const float* __restrict__ src, u16* __restrict__ dst) {
  int r = blockIdx.x, ci = threadIdx.x;     // grid 1024, block 512; rows >= 1000 are zero pad
  float v = (r < 1000) ? src[(size_t)r * 512 + ci] : 0.f;
  dst[(size_t)r * 512 + ci] = f2bf(v);
}

// ---------------- bf16 GEMM  C = A[M,K] @ B[N,K]^T  (128x128 tile, BK=32) ----------------
// MODE 1: fp32 row-major C[M,ldc], cols < nlimit.  MODE 2: bf16 transposed C[N][ldc=Mtotal].
template<int MODE>
__global__ __launch_bounds__(256, 1) void gemm_bt(const u16* __restrict__ A, const u16* __restrict__ B,
                                                  void* __restrict__ Cout, int K, int ldc, int nlimit) {
  __shared__ __align__(16) u16 smem[16 * 512];
  const int bm = blockIdx.x * 128;
  const int bn = blockIdx.y * 128;
  const int tid = threadIdx.x;
  const int w = tid >> 6;
  const int lane = tid & 63;
  const int r = lane & 15;
  const int q = lane >> 4;
  const int wm = w & 1, wn = w >> 1;

  f32x4 acc[4][4];
#pragma unroll
  for (int i = 0; i < 4; ++i)
#pragma unroll
    for (int j = 0; j < 4; ++j) acc[i][j] = (f32x4){0.f, 0.f, 0.f, 0.f};

  const u16* gA0 = A + (size_t)(bm + w * 16 + r) * K + q * 8;
  const u16* gA1 = A + (size_t)(bm + (w + 4) * 16 + r) * K + q * 8;
  const u16* gB0 = B + (size_t)(bn + w * 16 + r) * K + q * 8;
  const u16* gB1 = B + (size_t)(bn + (w + 4) * 16 + r) * K + q * 8;
  u16* As = smem;
  u16* Bs = smem + 8 * 512;

  for (int k0 = 0; k0 < K; k0 += 32) {
    stage16(gA0 + k0, As + w * 512);
    stage16(gA1 + k0, As + (w + 4) * 512);
    stage16(gB0 + k0, Bs + w * 512);
    stage16(gB1 + k0, Bs + (w + 4) * 512);
    __syncthreads();
    bf16x8 af[4], bf_[4];
#pragma unroll
    for (int mi = 0; mi < 4; ++mi) af[mi] = *(const bf16x8*)(As + (wm * 4 + mi) * 512 + lane * 8);
#pragma unroll
    for (int ni = 0; ni < 4; ++ni) bf_[ni] = *(const bf16x8*)(Bs + (wn * 4 + ni) * 512 + lane * 8);
#pragma unroll
    for (int mi = 0; mi < 4; ++mi)
#pragma unroll
      for (int ni = 0; ni < 4; ++ni)
        acc[mi][ni] = __builtin_amdgcn_mfma_f32_16x16x32_bf16(af[mi], bf_[ni], acc[mi][ni], 0, 0, 0);
    __syncthreads();
  }
  const int row0 = bm + wm * 64;
  const int col0 = bn + wn * 64;
#pragma unroll
  for (int mi = 0; mi < 4; ++mi)
#pragma unroll
    for (int ni = 0; ni < 4; ++ni) {
      int cc = col0 + ni * 16 + r;            // C/D: col=lane&15, row=(lane>>4)*4+reg
      int rr = row0 + mi * 16 + q * 4;
      if (MODE == 1) {
#pragma unroll
        for (int i = 0; i < 4; ++i)
          if (cc < nlimit) ((float*)Cout)[(size_t)(rr + i) * ldc + cc] = acc[mi][ni][i];
      } else {  // transposed bf16: CT[cc][rr..rr+3] as one 8B store
        u64 pk = (u64)f2bf(acc[mi][ni][0]) | ((u64)f2bf(acc[mi][ni][1]) << 16) |
                 ((u64)f2bf(acc[mi][ni][2]) << 32) | ((u64)f2bf(acc[mi][ni][3]) << 48);
        *(u64*)((u16*)Cout + (size_t)cc * ldc + rr) = pk;
      }
    }
}

// ---------------- per-row sum/sumsq over gatesT (1536 rows x 64000), contiguous ----------------
__global__ __launch_bounds__(256, 1) void rowstats(const u16* __restrict__ G,
                                                   float* __restrict__ sum, float* __restrict__ sumsq) {
  const int n = blockIdx.x;
  const u16* row = G + (size_t)n * 64000;
  float s = 0.f, ss = 0.f;
  for (int idx = threadIdx.x * 8; idx < 64000; idx += 2048) {
    union { bf16x8 v; u16 e[8]; } u;
    u.v = *(const bf16x8*)(row + idx);
#pragma unroll
    for (int e = 0; e < 8; ++e) { float f = bf2f(u.e[e]); s += f; ss += f * f; }
  }
#pragma unroll
  for (int o = 32; o > 0; o >>= 1) { s += __shfl_xor(s, o); ss += __shfl_xor(ss, o); }
  __shared__ float ls[4], lss[4];
  if ((threadIdx.x & 63) == 0) { ls[threadIdx.x >> 6] = s; lss[threadIdx.x >> 6] = ss; }
  __syncthreads();
  if (threadIdx.x == 0) {
    sum[n]   = ls[0] + ls[1] + ls[2] + ls[3];
    sumsq[n] = lss[0] + lss[1] + lss[2] + lss[3];
  }
}

// ---------------- per-column sum/sumsq over fp32 scores (64000 x 1000) ----------------
__global__ __launch_bounds__(256, 1) void colstats_f32(const float* __restrict__ X, int ld, int ncols,
                                                       float* __restrict__ sum, float* __restrict__ sumsq) {
  const int col = blockIdx.x * 128 + (threadIdx.x & 127);
  const int half = threadIdx.x >> 7;
  const int r0 = blockIdx.y * 2000;
  float s = 0.f, ss = 0.f;
  if (col < ncols) {
    for (int rr = r0 + half; rr < r0 + 2000; rr += 2) {
      float v = X[(size_t)rr * ld + col]; s += v; ss += v * v;
    }
  }
  __shared__ float ls[128], lss[128];
  if (half) { ls[threadIdx.x & 127] = s; lss[threadIdx.x & 127] = ss; }
  __syncthreads();
  if (!half && col < ncols) {
    s += ls[threadIdx.x]; ss += lss[threadIdx.x];
    atomicAdd(&sum[col], s); atomicAdd(&sumsq[col], ss);
  }
}

__global__ void fin_gate(const float* __restrict__ sum, const float* __restrict__ sq,
                         const float* gh, const float* bh, const float* gz, const float* bz,
                         const float* gr, const float* br, float* __restrict__ a, float* __restrict__ c) {
  int j = blockIdx.x * 256 + threadIdx.x;
  if (j >= 1536) return;
  float m = sum[j] * (1.f / 64000.f);
  float v = sq[j] * (1.f / 64000.f) - m * m;
  int seg = j >> 9, jj = j & 511;
  float gg = seg == 0 ? gh[jj] : seg == 1 ? gz[jj] : gr[jj];
  float bb = seg == 0 ? bh[jj] : seg == 1 ? bz[jj] : br[jj];
  float aa = gg * rsqrtf(v + 1e-5f);
  a[j] = aa; c[j] = bb - m * aa;
}

__global__ void fin_score(const float* __restrict__ sum, const float* __restrict__ sq,
                          const float* __restrict__ gfp, const float* __restrict__ bfp,
                          float* __restrict__ a, float* __restrict__ c) {
  int j = blockIdx.x * 256 + threadIdx.x;
  if (j >= 1000) return;
  float m = sum[j] * (1.f / 64000.f);
  float v = sq[j] * (1.f / 64000.f) - m * m;
  float aa = gfp[j] * rsqrtf(v + 1e-5f);
  a[j] = aa; c[j] = bfp[j] - m * aa;
}

// ---------------- persistent GRU scan: 32 WGs x 4 waves, tag-in-atom exchange ----------------
// Exchange atoms are u32 = (tag16 << 16) | bf16 value. No flags, no barriers: consumers
// speculatively load, verify every tag, and retry (wave-uniform) until the full fragment
// set for this wave's 16 batch rows carries the expected step tag. hx/rhx are
// double-buffered by step parity; a producer of step t+2 can only overwrite buffer (t&1)
// after it validated tags t+1 from every WG, which in turn requires every WG to have
// finished consuming buffer (t&1) -> overwrite race excluded. Memset at launch makes
// tag0/value0 == valid h_0 = 0 and kills stale tags across launches.
__global__ __launch_bounds__(256, 1) void scan_kernel(
    const u16* __restrict__ gatesT,              // (1536, 64000) bf16 transposed projections (in d_out)
    const float* __restrict__ Uz, const float* __restrict__ Ur, const float* __restrict__ Uh,
    const float* __restrict__ acoef, const float* __restrict__ ccoef,
    u16* __restrict__ hall,                      // (1001*64,512) bf16, write-only here (classifier input)
    u32* __restrict__ hx,                        // [2][64][512] tagged h
    u32* __restrict__ rhx) {                     // [2][64][512] tagged r*h
  __shared__ __align__(16) u16 Us[3][16][520];
  __shared__ float co[6][16];
  const int g = blockIdx.x;
  const int j0 = g * 16;
  const int tid = threadIdx.x;
  const int w = tid >> 6;         // wave -> batch rows [16w,16w+16)
  const int lane = tid & 63;
  const int r = lane & 15;
  const int q = lane >> 4;

  for (int idx = tid; idx < 3 * 16 * 512; idx += 256) {
    int u = idx >> 13;
    int rem = idx & 8191;
    int j = rem >> 9;
    int k = rem & 511;
    const float* U = (u == 0) ? Uz : (u == 1) ? Ur : Uh;
    Us[u][j][k] = f2bf(U[(size_t)(j0 + j) * 512 + k]);
  }
  if (tid < 16) {
    co[0][tid] = acoef[512 + j0 + tid];  co[1][tid] = ccoef[512 + j0 + tid];   // z
    co[2][tid] = acoef[1024 + j0 + tid]; co[3][tid] = ccoef[1024 + j0 + tid];  // r
    co[4][tid] = acoef[j0 + tid];        co[5][tid] = ccoef[j0 + tid];         // h
  }
  __syncthreads();
  const float az = co[0][r], cz = co[1][r], ar = co[2][r], cr = co[3][r];
  const float ah = co[4][r], ch = co[5][r];

  // gate rows for this lane (transposed layout: row j, 64000 columns = (t-1)*64 + b)
  const u16* gRowH = gatesT + (size_t)(j0 + r) * 64000;
  const u16* gRowZ = gatesT + (size_t)(512 + j0 + r) * 64000;
  const u16* gRowR = gatesT + (size_t)(1024 + j0 + r) * 64000;

  const int arow_off = (w * 16 + r) * 512 + q * 8;      // consumer base (u32 units)
  const int prow0 = (w * 16 + q * 4) * 512 + j0 + r;    // producer base (row w*16+q*4, col j0+r)

  float hp[4] = {0.f, 0.f, 0.f, 0.f};   // own h slice: rows w*16+q*4+i, col j0+r

  for (int t = 1; t <= S_LEN; ++t) {
    const int ct = (t - 1) * 64 + w * 16 + q * 4;
    // early plain loads of this step's gates
    const u64 wzq = *(const u64*)(gRowZ + ct);
    const u64 wrq = *(const u64*)(gRowR + ct);
    const u64 whq = *(const u64*)(gRowH + ct);

    // ---- phase A: z, r from h_{t-1}; publish r*h ----
    const u32* hsrc = hx + (size_t)((t - 1) & 1) * (64 * 512) + arow_off;
    const u32 tgA = (u32)(t - 1) << 16;
    const u64 expA = (u64)tgA | ((u64)tgA << 32);
    f32x4 accz, accr;
    for (;;) {
      accz = (f32x4){0.f, 0.f, 0.f, 0.f};
      accr = (f32x4){0.f, 0.f, 0.f, 0.f};
      u64 bad = 0;
#pragma unroll
      for (int ks = 0; ks < 16; ++ks) {
        u64 a0 = ld8(hsrc + ks * 32);
        u64 a1 = ld8(hsrc + ks * 32 + 2);
        u64 a2 = ld8(hsrc + ks * 32 + 4);
        u64 a3 = ld8(hsrc + ks * 32 + 6);
        bad |= (a0 ^ expA) | (a1 ^ expA);
        bad |= (a2 ^ expA) | (a3 ^ expA);
        union { u32 p[4]; bf16x8 v; } f;
        f.p[0] = ((u32)a0 & 0xFFFFu) | ((u32)(a0 >> 32) << 16);
        f.p[1] = ((u32)a1 & 0xFFFFu) | ((u32)(a1 >> 32) << 16);
        f.p[2] = ((u32)a2 & 0xFFFFu) | ((u32)(a2 >> 32) << 16);
        f.p[3] = ((u32)a3 & 0xFFFFu) | ((u32)(a3 >> 32) << 16);
        bf16x8 bz = *(const bf16x8*)(&Us[0][r][ks * 32 + q * 8]);
        bf16x8 br2 = *(const bf16x8*)(&Us[1][r][ks * 32 + q * 8]);
        accz = __builtin_amdgcn_mfma_f32_16x16x32_bf16(f.v, bz, accz, 0, 0, 0);
        accr = __builtin_amdgcn_mfma_f32_16x16x32_bf16(f.v, br2, accr, 0, 0, 0);
      }
      if (__all((bad & TAGMASK) == 0ull)) break;   // wave-uniform: MFMA needs all lanes fresh
      __builtin_amdgcn_s_sleep(2);
    }
    const u32 tgT = (u32)t << 16;
    u32* rdst = rhx + (size_t)(t & 1) * (64 * 512) + prow0;
    float zv[4];
#pragma unroll
    for (int i = 0; i < 4; ++i) {
      float wz = bf2f((u16)(wzq >> (16 * i)));
      float wr = bf2f((u16)(wrq >> (16 * i)));
      zv[i] = sigm(accz[i] + wz * az + cz);
      float rv = sigm(accr[i] + wr * ar + cr);
      st4(rdst + i * 512, tgT | (u32)f2bf(rv * hp[i]));
    }

    // ---- phase B: hcand from r*h; publish h_t ----
    const u32* rsrc = rhx + (size_t)(t & 1) * (64 * 512) + arow_off;
    const u64 expB = (u64)tgT | ((u64)tgT << 32);
    f32x4 acch;
    for (;;) {
      acch = (f32x4){0.f, 0.f, 0.f, 0.f};
      u64 bad = 0;
#pragma unroll
      for (int ks = 0; ks < 16; ++ks) {
        u64 a0 = ld8(rsrc + ks * 32);
        u64 a1 = ld8(rsrc + ks * 32 + 2);
        u64 a2 = ld8(rsrc + ks * 32 + 4);
        u64 a3 = ld8(rsrc + ks * 32 + 6);
        bad |= (a0 ^ expB) | (a1 ^ expB);
        bad |= (a2 ^ expB) | (a3 ^ expB);
        union { u32 p[4]; bf16x8 v; } f;
        f.p[0] = ((u32)a0 & 0xFFFFu) | ((u32)(a0 >> 32) << 16);
        f.p[1] = ((u32)a1 & 0xFFFFu) | ((u32)(a1 >> 32) << 16);
        f.p[2] = ((u32)a2 & 0xFFFFu) | ((u32)(a2 >> 32) << 16);
        f.p[3] = ((u32)a3 & 0xFFFFu) | ((u32)(a3 >> 32) << 16);
        bf16x8 bh = *(const bf16x8*)(&Us[2][r][ks * 32 + q * 8]);
        acch = __builtin_amdgcn_mfma_f32_16x16x32_bf16(f.v, bh, acch, 0, 0, 0);
      }
      if (__all((bad & TAGMASK) == 0ull)) break;
      __builtin_amdgcn_s_sleep(2);
    }
    u16* hrow = hall + (size_t)t * (64 * 512);
    u32* hdst = hx + (size_t)(t & 1) * (64 * 512) + prow0;
#pragma unroll
    for (int i = 0; i < 4; ++i) {
      float wh = bf2f((u16)(whq >> (16 * i)));
      float hc = tanh_(acch[i] + wh * ah + ch);
      float hn = zv[i] * hp[i] + (1.f - zv[i]) * hc;
      u16 hb = f2bf(hn);
      hp[i] = bf2f(hb);                              // carry own slice (bf16-rounded)
      hrow[(size_t)(w * 16 + q * 4 + i) * 512 + j0 + r] = hb;   // plain store, off critical path
      st4(hdst + i * 512, tgT | (u32)hb);
    }
  }
}

// ---------------- BN + log_softmax, in place on fp32 scores ----------------
__global__ __launch_bounds__(256, 1) void logsoftmax_k(float* __restrict__ S,
                                                       const float* __restrict__ a, const float* __restrict__ c) {
  __shared__ float as_[1000], cs_[1000];
  for (int i = threadIdx.x; i < 1000; i += 256) { as_[i] = a[i]; cs_[i] = c[i]; }
  __syncthreads();
  const int w = threadIdx.x >> 6, lane = threadIdx.x & 63;
  for (int it = 0; it < 4; ++it) {
    const int row = blockIdx.x * 16 + it * 4 + w;
    float* Srow = S + (size_t)row * 1000;
    float tv[16];
    float mx = -3.0e38f;
#pragma unroll
    for (int qq = 0; qq < 16; ++qq) {
      int j = lane + qq * 64;
      float v = -3.0e38f;
      if (j < 1000) v = as_[j] * Srow[j] + cs_[j];
      tv[qq] = v;
      mx = fmaxf(mx, v);
    }
#pragma unroll
    for (int o = 32; o > 0; o >>= 1) mx = fmaxf(mx, __shfl_xor(mx, o));
    float sm = 0.f;
#pragma unroll
    for (int qq = 0; qq < 16; ++qq) sm += __expf(tv[qq] - mx);
#pragma unroll
    for (int o = 32; o > 0; o >>= 1) sm += __shfl_xor(sm, o);
    float lse = mx + __logf(sm);
#pragma unroll
    for (int qq = 0; qq < 16; ++qq) {
      int j = lane + qq * 64;
      if (j < 1000) Srow[j] = tv[qq] - lse;
    }
  }
}

// ---------------- launch ----------------
extern "C" void kernel_launch(void* const* d_in, const int* in_sizes, int n_in,
                              void* d_out, int out_size, void* d_ws, size_t ws_size,
                              hipStream_t stream) {
  const float* x  = (const float*)d_in[0];
  const float* Wh = (const float*)d_in[1];
  const float* Wz = (const float*)d_in[2];
  const float* Wr = (const float*)d_in[3];
  const float* Uh = (const float*)d_in[4];
  const float* Uz = (const float*)d_in[5];
  const float* Ur = (const float*)d_in[6];
  const float* gh = (const float*)d_in[7];
  const float* bh = (const float*)d_in[8];
  const float* gz = (const float*)d_in[9];
  const float* bz = (const float*)d_in[10];
  const float* gr = (const float*)d_in[11];
  const float* br = (const float*)d_in[12];
  const float* Wf = (const float*)d_in[13];
  const float* gf = (const float*)d_in[14];
  const float* bfp = (const float*)d_in[15];

  uint8_t* ws = (uint8_t*)d_ws;
  u16* hall = (u16*)(ws + OFF_HALL);
  u16* xb   = (u16*)(ws + OFF_HALL);   // alias: xb dead before hall is written
  u16* wcat = (u16*)(ws + OFF_WCAT);
  u16* wfb  = (u16*)(ws + OFF_WFB);
  u32* hx   = (u32*)(ws + OFF_HX);     // aliases wcat (dead after proj GEMM)
  u32* rhx  = (u32*)(ws + OFF_RHX);    // aliases wcat
  float* gsum = (float*)(ws + OFF_GSUM);
  float* gsq  = (float*)(ws + OFF_GSQ);
  float* aall = (float*)(ws + OFF_AALL);
  float* call = (float*)(ws + OFF_CALL);
  float* ssum = (float*)(ws + OFF_SSUM);
  float* ssq  = (float*)(ws + OFF_SSQ);
  float* af   = (float*)(ws + OFF_AF);
  float* cf   = (float*)(ws + OFF_CF);

  u16* gatesT = (u16*)d_out;     // (1536, 64000) bf16, dead after scan
  float* scores = (float*)d_out; // (64000,1000) fp32, written by classifier GEMM

  hipMemsetAsync(ws + OFF_SSUM, 0, (size_t)STATS_ZERO_BYTES, stream);

  cvt_pad<<<dim3(64000), dim3(448), 0, stream>>>(x, xb, 440, 448);
  cvt_pad<<<dim3(512), dim3(448), 0, stream>>>(Wh, wcat, 440, 448);
  cvt_pad<<<dim3(512), dim3(448), 0, stream>>>(Wz, wcat + 512 * 448, 440, 448);
  cvt_pad<<<dim3(512), dim3(448), 0, stream>>>(Wr, wcat + 1024 * 448, 440, 448);
  cvt_wf<<<dim3(1024), dim3(512), 0, stream>>>(Wf, wfb);

  gemm_bt<2><<<dim3(500, 12), dim3(256), 0, stream>>>(xb, wcat, (void*)gatesT, 448, 64000, 1536);

  rowstats<<<dim3(1536), dim3(256), 0, stream>>>(gatesT, gsum, gsq);
  fin_gate<<<dim3(6), dim3(256), 0, stream>>>(gsum, gsq, gh, bh, gz, bz, gr, br, aall, call);

  // wcat is dead from here on: zero the aliased tagged exchange buffers.
  // (stream-ordered after the GEMM; tag0|val0 == valid h_0 = 0; clears stale tags
  //  from any previous launch)
  hipMemsetAsync(ws + OFF_HX, 0, (size_t)(SZ_HX + SZ_RHX), stream);

  scan_kernel<<<dim3(NWG), dim3(256), 0, stream>>>(gatesT, Uz, Ur, Uh, aall, call, hall, hx, rhx);

  gemm_bt<1><<<dim3(500, 8), dim3(256), 0, stream>>>(hall + 64 * 512, wfb, (void*)scores, 512, 1000, 1000);

  colstats_f32<<<dim3(8, 32), dim3(256), 0, stream>>>(scores, 1000, 1000, ssum, ssq);
  fin_score<<<dim3(4), dim3(256), 0, stream>>>(ssum, ssq, gf, bfp, af, cf);

  logsoftmax_k<<<dim3(4000), dim3(256), 0, stream>>>(scores, af, cf);
}

// Round 3
// 19850.636 us; speedup vs baseline: 1.7685x; 1.7685x over previous
//
#include <hip/hip_runtime.h>
#include <cstdint>

typedef unsigned short u16;
typedef unsigned u32;
typedef unsigned long long u64;
typedef __attribute__((ext_vector_type(8))) short bf16x8;
typedef __attribute__((ext_vector_type(4))) float f32x4;

#define S_LEN 1000
#define NWG   32               // scan workgroups (each owns 16 H-columns)

// ---------------- ws layout (bytes) ----------------
// Footprint kept strictly within the verified bound: tagged exchange buffers alias
// the wcat region, which is dead after gemm_bt<2>.
#define OFF_HALL   0ull                         // (1001*64, 512) bf16 hidden states; xb aliases here (dead before scan)
#define SZ_HALL    (1001ull*64*512*2)
#define OFF_WCAT   (OFF_HALL + SZ_HALL)         // (1536, 448) bf16  [Wh;Wz;Wr] K-padded (dead after proj GEMM)
#define SZ_WCAT    (1536ull*448*2)
#define OFF_HX     (OFF_WCAT)                   // [2][64][512] u32 tagged h exchange (tag16|bf16) — aliases wcat
#define SZ_HX      (2ull*64*512*4)
#define OFF_RHX    (OFF_HX + SZ_HX)             // [2][64][512] u32 tagged r*h exchange — aliases wcat
#define SZ_RHX     (2ull*64*512*4)
#define OFF_WFB    (OFF_WCAT + SZ_WCAT)         // (1024, 512) bf16  Wf row-padded
#define SZ_WFB     (1024ull*512*2)
#define OFF_GSUM   (OFF_WFB + SZ_WFB)
#define OFF_GSQ    (OFF_GSUM + 1536*4)
#define OFF_AALL   (OFF_GSQ  + 1536*4)
#define OFF_CALL   (OFF_AALL + 1536*4)
#define OFF_SSUM   (OFF_CALL + 1536*4)
#define OFF_SSQ    (OFF_SSUM + 1024*4)
#define OFF_AF     (OFF_SSQ  + 1024*4)
#define OFF_CF     (OFF_AF   + 1024*4)
#define STATS_ZERO_BYTES (OFF_CF + 1024*4 - OFF_SSUM)

#define TAGMASK 0xFFFF0000FFFF0000ull

// ---------------- helpers ----------------
__device__ __forceinline__ float bf2f(u16 u) {
  union { unsigned u; float f; } v; v.u = ((unsigned)u) << 16; return v.f;
}
__device__ __forceinline__ u16 f2bf(float f) {   // RNE
  union { float f; unsigned u; } v; v.f = f;
  unsigned r = (v.u + 0x7fffu + ((v.u >> 16) & 1u)) >> 16;
  return (u16)r;
}
__device__ __forceinline__ float sigm(float x) { return 1.f / (1.f + __expf(-x)); }
__device__ __forceinline__ float tanh_(float x) {
  float e = __expf(-2.f * fabsf(x));
  float r = (1.f - e) / (1.f + e);
  return x >= 0.f ? r : -r;
}

// LLC-coherent (device-scope, no-fence) exchange primitives
__device__ __forceinline__ u64 ld8(const u32* p) {
  return __hip_atomic_load((const u64*)p, __ATOMIC_RELAXED, __HIP_MEMORY_SCOPE_AGENT);
}
__device__ __forceinline__ u32 ld4(const u32* p) {
  return __hip_atomic_load(p, __ATOMIC_RELAXED, __HIP_MEMORY_SCOPE_AGENT);
}
__device__ __forceinline__ void st4(u32* p, u32 v) {
  __hip_atomic_store(p, v, __ATOMIC_RELAXED, __HIP_MEMORY_SCOPE_AGENT);
}

// async global->LDS, 16B/lane
__device__ __forceinline__ void stage16(const u16* g, u16* l) {
  __builtin_amdgcn_global_load_lds((const __attribute__((address_space(1))) unsigned int*)(g),
                                   (__attribute__((address_space(3))) unsigned int*)(l), 16, 0, 0);
}

// ---------------- fp32 -> bf16 converts with padding ----------------
__global__ void cvt_pad(const float* __restrict__ src, u16* __restrict__ dst, int incols, int outcols) {
  int r = blockIdx.x, ci = threadIdx.x;
  float v = (ci < incols) ? src[(size_t)r * incols + ci] : 0.f;
  dst[(size_t)r * outcols + ci] = f2bf(v);
}
__global__ void cvt_wf(const float* __restrict__ src, u16* __restrict__ dst) {
  int r = blockIdx.x, ci = threadIdx.x;     // grid 1024, block 512; rows >= 1000 are zero pad
  float v = (r < 1000) ? src[(size_t)r * 512 + ci] : 0.f;
  dst[(size_t)r * 512 + ci] = f2bf(v);
}

// ---------------- bf16 GEMM  C = A[M,K] @ B[N,K]^T  (128x128 tile, BK=32) ----------------
template<int MODE>
__global__ __launch_bounds__(256, 1) void gemm_bt(const u16* __restrict__ A, const u16* __restrict__ B,
                                                  void* __restrict__ Cout, int K, int ldc, int nlimit) {
  __shared__ __align__(16) u16 smem[16 * 512];
  const int bm = blockIdx.x * 128;
  const int bn = blockIdx.y * 128;
  const int tid = threadIdx.x;
  const int w = tid >> 6;
  const int lane = tid & 63;
  const int r = lane & 15;
  const int q = lane >> 4;
  const int wm = w & 1, wn = w >> 1;

  f32x4 acc[4][4];
#pragma unroll
  for (int i = 0; i < 4; ++i)
#pragma unroll
    for (int j = 0; j < 4; ++j) acc[i][j] = (f32x4){0.f, 0.f, 0.f, 0.f};

  const u16* gA0 = A + (size_t)(bm + w * 16 + r) * K + q * 8;
  const u16* gA1 = A + (size_t)(bm + (w + 4) * 16 + r) * K + q * 8;
  const u16* gB0 = B + (size_t)(bn + w * 16 + r) * K + q * 8;
  const u16* gB1 = B + (size_t)(bn + (w + 4) * 16 + r) * K + q * 8;
  u16* As = smem;
  u16* Bs = smem + 8 * 512;

  for (int k0 = 0; k0 < K; k0 += 32) {
    stage16(gA0 + k0, As + w * 512);
    stage16(gA1 + k0, As + (w + 4) * 512);
    stage16(gB0 + k0, Bs + w * 512);
    stage16(gB1 + k0, Bs + (w + 4) * 512);
    __syncthreads();
    bf16x8 af[4], bf_[4];
#pragma unroll
    for (int mi = 0; mi < 4; ++mi) af[mi] = *(const bf16x8*)(As + (wm * 4 + mi) * 512 + lane * 8);
#pragma unroll
    for (int ni = 0; ni < 4; ++ni) bf_[ni] = *(const bf16x8*)(Bs + (wn * 4 + ni) * 512 + lane * 8);
#pragma unroll
    for (int mi = 0; mi < 4; ++mi)
#pragma unroll
      for (int ni = 0; ni < 4; ++ni)
        acc[mi][ni] = __builtin_amdgcn_mfma_f32_16x16x32_bf16(af[mi], bf_[ni], acc[mi][ni], 0, 0, 0);
    __syncthreads();
  }
  const int row0 = bm + wm * 64;
  const int col0 = bn + wn * 64;
#pragma unroll
  for (int mi = 0; mi < 4; ++mi)
#pragma unroll
    for (int ni = 0; ni < 4; ++ni) {
      int cc = col0 + ni * 16 + r;            // C/D: col=lane&15, row=(lane>>4)*4+reg
      int rr = row0 + mi * 16 + q * 4;
      if (MODE == 1) {
#pragma unroll
        for (int i = 0; i < 4; ++i)
          if (cc < nlimit) ((float*)Cout)[(size_t)(rr + i) * ldc + cc] = acc[mi][ni][i];
      } else {  // transposed bf16: CT[cc][rr..rr+3] as one 8B store
        u64 pk = (u64)f2bf(acc[mi][ni][0]) | ((u64)f2bf(acc[mi][ni][1]) << 16) |
                 ((u64)f2bf(acc[mi][ni][2]) << 32) | ((u64)f2bf(acc[mi][ni][3]) << 48);
        *(u64*)((u16*)Cout + (size_t)cc * ldc + rr) = pk;
      }
    }
}

// ---------------- per-row sum/sumsq over gatesT (1536 rows x 64000) ----------------
__global__ __launch_bounds__(256, 1) void rowstats(const u16* __restrict__ G,
                                                   float* __restrict__ sum, float* __restrict__ sumsq) {
  const int n = blockIdx.x;
  const u16* row = G + (size_t)n * 64000;
  float s = 0.f, ss = 0.f;
  for (int idx = threadIdx.x * 8; idx < 64000; idx += 2048) {
    union { bf16x8 v; u16 e[8]; } u;
    u.v = *(const bf16x8*)(row + idx);
#pragma unroll
    for (int e = 0; e < 8; ++e) { float f = bf2f(u.e[e]); s += f; ss += f * f; }
  }
#pragma unroll
  for (int o = 32; o > 0; o >>= 1) { s += __shfl_xor(s, o); ss += __shfl_xor(ss, o); }
  __shared__ float ls[4], lss[4];
  if ((threadIdx.x & 63) == 0) { ls[threadIdx.x >> 6] = s; lss[threadIdx.x >> 6] = ss; }
  __syncthreads();
  if (threadIdx.x == 0) {
    sum[n]   = ls[0] + ls[1] + ls[2] + ls[3];
    sumsq[n] = lss[0] + lss[1] + lss[2] + lss[3];
  }
}

// ---------------- per-column sum/sumsq over fp32 scores (64000 x 1000) ----------------
__global__ __launch_bounds__(256, 1) void colstats_f32(const float* __restrict__ X, int ld, int ncols,
                                                       float* __restrict__ sum, float* __restrict__ sumsq) {
  const int col = blockIdx.x * 128 + (threadIdx.x & 127);
  const int half = threadIdx.x >> 7;
  const int r0 = blockIdx.y * 2000;
  float s = 0.f, ss = 0.f;
  if (col < ncols) {
    for (int rr = r0 + half; rr < r0 + 2000; rr += 2) {
      float v = X[(size_t)rr * ld + col]; s += v; ss += v * v;
    }
  }
  __shared__ float ls[128], lss[128];
  if (half) { ls[threadIdx.x & 127] = s; lss[threadIdx.x & 127] = ss; }
  __syncthreads();
  if (!half && col < ncols) {
    s += ls[threadIdx.x]; ss += lss[threadIdx.x];
    atomicAdd(&sum[col], s); atomicAdd(&sumsq[col], ss);
  }
}

__global__ void fin_gate(const float* __restrict__ sum, const float* __restrict__ sq,
                         const float* gh, const float* bh, const float* gz, const float* bz,
                         const float* gr, const float* br, float* __restrict__ a, float* __restrict__ c) {
  int j = blockIdx.x * 256 + threadIdx.x;
  if (j >= 1536) return;
  float m = sum[j] * (1.f / 64000.f);
  float v = sq[j] * (1.f / 64000.f) - m * m;
  int seg = j >> 9, jj = j & 511;
  float gg = seg == 0 ? gh[jj] : seg == 1 ? gz[jj] : gr[jj];
  float bb = seg == 0 ? bh[jj] : seg == 1 ? bz[jj] : br[jj];
  float aa = gg * rsqrtf(v + 1e-5f);
  a[j] = aa; c[j] = bb - m * aa;
}

__global__ void fin_score(const float* __restrict__ sum, const float* __restrict__ sq,
                          const float* __restrict__ gfp, const float* __restrict__ bfp,
                          float* __restrict__ a, float* __restrict__ c) {
  int j = blockIdx.x * 256 + threadIdx.x;
  if (j >= 1000) return;
  float m = sum[j] * (1.f / 64000.f);
  float v = sq[j] * (1.f / 64000.f) - m * m;
  float aa = gfp[j] * rsqrtf(v + 1e-5f);
  a[j] = aa; c[j] = bfp[j] - m * aa;
}

// ---------------- persistent GRU scan: tag-in-atom exchange + cheap sentinel detect ----------------
// Atoms are u32 = (tag16 << 16) | bf16. Correctness rests ONLY on the per-atom tags
// (full pass validates everything, retries if stale). The sentinel poll is a latency
// hint: each consumer wave spins on 32 atoms (one per producer WG — that producer
// wave's LAST-issued store, row w*16+15, col g'*16+15), 128 B/poll, before doing the
// single 32 KB tagged pass. This keeps detection traffic ~256x below r2's full-pass
// spinning (which inflated LLC latency ~5x) while still collapsing the old design's
// drain+flag+poll round trips.
__global__ __launch_bounds__(256, 1) void scan_kernel(
    const u16* __restrict__ gatesT,              // (1536, 64000) bf16 transposed projections (in d_out)
    const float* __restrict__ Uz, const float* __restrict__ Ur, const float* __restrict__ Uh,
    const float* __restrict__ acoef, const float* __restrict__ ccoef,
    u16* __restrict__ hall,                      // (1001*64,512) bf16, write-only here (classifier input)
    u32* __restrict__ hx,                        // [2][64][512] tagged h
    u32* __restrict__ rhx) {                     // [2][64][512] tagged r*h
  __shared__ __align__(16) u16 Us[3][16][520];
  __shared__ float co[6][16];
  const int g = blockIdx.x;
  const int j0 = g * 16;
  const int tid = threadIdx.x;
  const int w = tid >> 6;         // wave -> batch rows [16w,16w+16)
  const int lane = tid & 63;
  const int r = lane & 15;
  const int q = lane >> 4;

  for (int idx = tid; idx < 3 * 16 * 512; idx += 256) {
    int u = idx >> 13;
    int rem = idx & 8191;
    int j = rem >> 9;
    int k = rem & 511;
    const float* U = (u == 0) ? Uz : (u == 1) ? Ur : Uh;
    Us[u][j][k] = f2bf(U[(size_t)(j0 + j) * 512 + k]);
  }
  if (tid < 16) {
    co[0][tid] = acoef[512 + j0 + tid];  co[1][tid] = ccoef[512 + j0 + tid];   // z
    co[2][tid] = acoef[1024 + j0 + tid]; co[3][tid] = ccoef[1024 + j0 + tid];  // r
    co[4][tid] = acoef[j0 + tid];        co[5][tid] = ccoef[j0 + tid];         // h
  }
  __syncthreads();
  const float az = co[0][r], cz = co[1][r], ar = co[2][r], cr = co[3][r];
  const float ah = co[4][r], ch = co[5][r];

  const u16* gRowH = gatesT + (size_t)(j0 + r) * 64000;
  const u16* gRowZ = gatesT + (size_t)(512 + j0 + r) * 64000;
  const u16* gRowR = gatesT + (size_t)(1024 + j0 + r) * 64000;

  const int arow_off = (w * 16 + r) * 512 + q * 8;      // consumer base (u32 units)
  const int prow0 = (w * 16 + q * 4) * 512 + j0 + r;    // producer base (row w*16+q*4, col j0+r)
  const int srow_off = (w * 16 + 15) * 512 + 15;        // sentinel row base + col15

  float hp[4] = {0.f, 0.f, 0.f, 0.f};   // own h slice: rows w*16+q*4+i, col j0+r

  for (int t = 1; t <= S_LEN; ++t) {
    const int ct = (t - 1) * 64 + w * 16 + q * 4;
    const u64 wzq = *(const u64*)(gRowZ + ct);
    const u64 wrq = *(const u64*)(gRowR + ct);
    const u64 whq = *(const u64*)(gRowH + ct);

    // ---- phase A: z, r from h_{t-1}; publish r*h ----
    const u32 tgA = (u32)(t - 1) << 16;
    const u32* hbase = hx + (size_t)((t - 1) & 1) * (64 * 512);
    // cheap sentinel detect: one atom per producer WG
    {
      const u32* sp = hbase + srow_off;
      for (;;) {
        u32 v = (lane < NWG) ? ld4(sp + lane * 16) : tgA;
        if (__all((v & 0xFFFF0000u) == tgA)) break;
        __builtin_amdgcn_s_sleep(1);
      }
    }
    const u32* hsrc = hbase + arow_off;
    const u64 expA = (u64)tgA | ((u64)tgA << 32);
    f32x4 accz, accr;
    for (;;) {
      accz = (f32x4){0.f, 0.f, 0.f, 0.f};
      accr = (f32x4){0.f, 0.f, 0.f, 0.f};
      u64 bad = 0;
#pragma unroll
      for (int ks = 0; ks < 16; ++ks) {
        u64 a0 = ld8(hsrc + ks * 32);
        u64 a1 = ld8(hsrc + ks * 32 + 2);
        u64 a2 = ld8(hsrc + ks * 32 + 4);
        u64 a3 = ld8(hsrc + ks * 32 + 6);
        bad |= (a0 ^ expA) | (a1 ^ expA);
        bad |= (a2 ^ expA) | (a3 ^ expA);
        union { u32 p[4]; bf16x8 v; } f;
        f.p[0] = ((u32)a0 & 0xFFFFu) | ((u32)(a0 >> 32) << 16);
        f.p[1] = ((u32)a1 & 0xFFFFu) | ((u32)(a1 >> 32) << 16);
        f.p[2] = ((u32)a2 & 0xFFFFu) | ((u32)(a2 >> 32) << 16);
        f.p[3] = ((u32)a3 & 0xFFFFu) | ((u32)(a3 >> 32) << 16);
        bf16x8 bz = *(const bf16x8*)(&Us[0][r][ks * 32 + q * 8]);
        bf16x8 br2 = *(const bf16x8*)(&Us[1][r][ks * 32 + q * 8]);
        accz = __builtin_amdgcn_mfma_f32_16x16x32_bf16(f.v, bz, accz, 0, 0, 0);
        accr = __builtin_amdgcn_mfma_f32_16x16x32_bf16(f.v, br2, accr, 0, 0, 0);
      }
      if (__all((bad & TAGMASK) == 0ull)) break;   // wave-uniform: MFMA needs all lanes fresh
      __builtin_amdgcn_s_sleep(1);
    }
    const u32 tgT = (u32)t << 16;
    u32* rdst = rhx + (size_t)(t & 1) * (64 * 512) + prow0;
    // r-gate + exchange stores FIRST (critical data into flight early)
    float zv[4];
#pragma unroll
    for (int i = 0; i < 4; ++i) {
      float wr = bf2f((u16)(wrq >> (16 * i)));
      float rv = sigm(accr[i] + wr * ar + cr);
      st4(rdst + i * 512, tgT | (u32)f2bf(rv * hp[i]));
    }
#pragma unroll
    for (int i = 0; i < 4; ++i) {
      float wz = bf2f((u16)(wzq >> (16 * i)));
      zv[i] = sigm(accz[i] + wz * az + cz);
    }

    // ---- phase B: hcand from r*h; publish h_t ----
    const u32* rbase = rhx + (size_t)(t & 1) * (64 * 512);
    {
      const u32* sp = rbase + srow_off;
      for (;;) {
        u32 v = (lane < NWG) ? ld4(sp + lane * 16) : tgT;
        if (__all((v & 0xFFFF0000u) == tgT)) break;
        __builtin_amdgcn_s_sleep(1);
      }
    }
    const u32* rsrc = rbase + arow_off;
    const u64 expB = (u64)tgT | ((u64)tgT << 32);
    f32x4 acch;
    for (;;) {
      acch = (f32x4){0.f, 0.f, 0.f, 0.f};
      u64 bad = 0;
#pragma unroll
      for (int ks = 0; ks < 16; ++ks) {
        u64 a0 = ld8(rsrc + ks * 32);
        u64 a1 = ld8(rsrc + ks * 32 + 2);
        u64 a2 = ld8(rsrc + ks * 32 + 4);
        u64 a3 = ld8(rsrc + ks * 32 + 6);
        bad |= (a0 ^ expB) | (a1 ^ expB);
        bad |= (a2 ^ expB) | (a3 ^ expB);
        union { u32 p[4]; bf16x8 v; } f;
        f.p[0] = ((u32)a0 & 0xFFFFu) | ((u32)(a0 >> 32) << 16);
        f.p[1] = ((u32)a1 & 0xFFFFu) | ((u32)(a1 >> 32) << 16);
        f.p[2] = ((u32)a2 & 0xFFFFu) | ((u32)(a2 >> 32) << 16);
        f.p[3] = ((u32)a3 & 0xFFFFu) | ((u32)(a3 >> 32) << 16);
        bf16x8 bh = *(const bf16x8*)(&Us[2][r][ks * 32 + q * 8]);
        acch = __builtin_amdgcn_mfma_f32_16x16x32_bf16(f.v, bh, acch, 0, 0, 0);
      }
      if (__all((bad & TAGMASK) == 0ull)) break;
      __builtin_amdgcn_s_sleep(1);
    }
    u16* hrow = hall + (size_t)t * (64 * 512);
    u32* hdst = hx + (size_t)(t & 1) * (64 * 512) + prow0;
    u16 hb4[4];
#pragma unroll
    for (int i = 0; i < 4; ++i) {
      float wh = bf2f((u16)(whq >> (16 * i)));
      float hc = tanh_(acch[i] + wh * ah + ch);
      float hn = zv[i] * hp[i] + (1.f - zv[i]) * hc;
      u16 hb = f2bf(hn);
      hb4[i] = hb;
      hp[i] = bf2f(hb);                              // carry own slice (bf16-rounded)
      st4(hdst + i * 512, tgT | (u32)hb);            // exchange store FIRST
    }
#pragma unroll
    for (int i = 0; i < 4; ++i)                      // hall (classifier input) after
      hrow[(size_t)(w * 16 + q * 4 + i) * 512 + j0 + r] = hb4[i];
  }
}

// ---------------- BN + log_softmax, in place on fp32 scores ----------------
__global__ __launch_bounds__(256, 1) void logsoftmax_k(float* __restrict__ S,
                                                       const float* __restrict__ a, const float* __restrict__ c) {
  __shared__ float as_[1000], cs_[1000];
  for (int i = threadIdx.x; i < 1000; i += 256) { as_[i] = a[i]; cs_[i] = c[i]; }
  __syncthreads();
  const int w = threadIdx.x >> 6, lane = threadIdx.x & 63;
  for (int it = 0; it < 4; ++it) {
    const int row = blockIdx.x * 16 + it * 4 + w;
    float* Srow = S + (size_t)row * 1000;
    float tv[16];
    float mx = -3.0e38f;
#pragma unroll
    for (int qq = 0; qq < 16; ++qq) {
      int j = lane + qq * 64;
      float v = -3.0e38f;
      if (j < 1000) v = as_[j] * Srow[j] + cs_[j];
      tv[qq] = v;
      mx = fmaxf(mx, v);
    }
#pragma unroll
    for (int o = 32; o > 0; o >>= 1) mx = fmaxf(mx, __shfl_xor(mx, o));
    float sm = 0.f;
#pragma unroll
    for (int qq = 0; qq < 16; ++qq) sm += __expf(tv[qq] - mx);
#pragma unroll
    for (int o = 32; o > 0; o >>= 1) sm += __shfl_xor(sm, o);
    float lse = mx + __logf(sm);
#pragma unroll
    for (int qq = 0; qq < 16; ++qq) {
      int j = lane + qq * 64;
      if (j < 1000) Srow[j] = tv[qq] - lse;
    }
  }
}

// ---------------- launch ----------------
extern "C" void kernel_launch(void* const* d_in, const int* in_sizes, int n_in,
                              void* d_out, int out_size, void* d_ws, size_t ws_size,
                              hipStream_t stream) {
  const float* x  = (const float*)d_in[0];
  const float* Wh = (const float*)d_in[1];
  const float* Wz = (const float*)d_in[2];
  const float* Wr = (const float*)d_in[3];
  const float* Uh = (const float*)d_in[4];
  const float* Uz = (const float*)d_in[5];
  const float* Ur = (const float*)d_in[6];
  const float* gh = (const float*)d_in[7];
  const float* bh = (const float*)d_in[8];
  const float* gz = (const float*)d_in[9];
  const float* bz = (const float*)d_in[10];
  const float* gr = (const float*)d_in[11];
  const float* br = (const float*)d_in[12];
  const float* Wf = (const float*)d_in[13];
  const float* gf = (const float*)d_in[14];
  const float* bfp = (const float*)d_in[15];

  uint8_t* ws = (uint8_t*)d_ws;
  u16* hall = (u16*)(ws + OFF_HALL);
  u16* xb   = (u16*)(ws + OFF_HALL);   // alias: xb dead before hall is written
  u16* wcat = (u16*)(ws + OFF_WCAT);
  u16* wfb  = (u16*)(ws + OFF_WFB);
  u32* hx   = (u32*)(ws + OFF_HX);     // aliases wcat (dead after proj GEMM)
  u32* rhx  = (u32*)(ws + OFF_RHX);    // aliases wcat
  float* gsum = (float*)(ws + OFF_GSUM);
  float* gsq  = (float*)(ws + OFF_GSQ);
  float* aall = (float*)(ws + OFF_AALL);
  float* call = (float*)(ws + OFF_CALL);
  float* ssum = (float*)(ws + OFF_SSUM);
  float* ssq  = (float*)(ws + OFF_SSQ);
  float* af   = (float*)(ws + OFF_AF);
  float* cf   = (float*)(ws + OFF_CF);

  u16* gatesT = (u16*)d_out;     // (1536, 64000) bf16, dead after scan
  float* scores = (float*)d_out; // (64000,1000) fp32, written by classifier GEMM

  hipMemsetAsync(ws + OFF_SSUM, 0, (size_t)STATS_ZERO_BYTES, stream);

  cvt_pad<<<dim3(64000), dim3(448), 0, stream>>>(x, xb, 440, 448);
  cvt_pad<<<dim3(512), dim3(448), 0, stream>>>(Wh, wcat, 440, 448);
  cvt_pad<<<dim3(512), dim3(448), 0, stream>>>(Wz, wcat + 512 * 448, 440, 448);
  cvt_pad<<<dim3(512), dim3(448), 0, stream>>>(Wr, wcat + 1024 * 448, 440, 448);
  cvt_wf<<<dim3(1024), dim3(512), 0, stream>>>(Wf, wfb);

  gemm_bt<2><<<dim3(500, 12), dim3(256), 0, stream>>>(xb, wcat, (void*)gatesT, 448, 64000, 1536);

  rowstats<<<dim3(1536), dim3(256), 0, stream>>>(gatesT, gsum, gsq);
  fin_gate<<<dim3(6), dim3(256), 0, stream>>>(gsum, gsq, gh, bh, gz, bz, gr, br, aall, call);

  // wcat is dead from here on: zero the aliased tagged exchange buffers
  // (tag0|val0 == valid h_0 = 0; clears stale tags from any previous launch)
  hipMemsetAsync(ws + OFF_HX, 0, (size_t)(SZ_HX + SZ_RHX), stream);

  scan_kernel<<<dim3(NWG), dim3(256), 0, stream>>>(gatesT, Uz, Ur, Uh, aall, call, hall, hx, rhx);

  gemm_bt<1><<<dim3(500, 8), dim3(256), 0, stream>>>(hall + 64 * 512, wfb, (void*)scores, 512, 1000, 1000);

  colstats_f32<<<dim3(8, 32), dim3(256), 0, stream>>>(scores, 1000, 1000, ssum, ssq);
  fin_score<<<dim3(4), dim3(256), 0, stream>>>(ssum, ssq, gf, bfp, af, cf);

  logsoftmax_k<<<dim3(4000), dim3(256), 0, stream>>>(scores, af, cf);
}

// Round 4
// 12739.834 us; speedup vs baseline: 2.7556x; 1.5582x over previous
//
#include <hip/hip_runtime.h>
#include <cstdint>

typedef unsigned short u16;
typedef unsigned u32;
typedef unsigned long long u64;
typedef __attribute__((ext_vector_type(8))) short bf16x8;
typedef __attribute__((ext_vector_type(4))) float f32x4;
typedef __attribute__((ext_vector_type(4))) unsigned u32x4;

#define S_LEN 1000
#define NWG   32               // scan workgroups (each owns 16 H-columns)

// ---------------- ws layout (bytes) ----------------
// Footprint kept strictly within the verified bound: tagged exchange buffers alias
// the wcat region, which is dead after gemm_bt<2>.
#define OFF_HALL   0ull                         // (1001*64, 512) bf16 hidden states; xb aliases here (dead before scan)
#define SZ_HALL    (1001ull*64*512*2)
#define OFF_WCAT   (OFF_HALL + SZ_HALL)         // (1536, 448) bf16  [Wh;Wz;Wr] K-padded (dead after proj GEMM)
#define SZ_WCAT    (1536ull*448*2)
#define OFF_HX     (OFF_WCAT)                   // [2][64][512] u32 tagged h exchange (tag16|bf16) — aliases wcat
#define SZ_HX      (2ull*64*512*4)
#define OFF_RHX    (OFF_HX + SZ_HX)             // [2][64][512] u32 tagged r*h exchange — aliases wcat
#define SZ_RHX     (2ull*64*512*4)
#define OFF_WFB    (OFF_WCAT + SZ_WCAT)         // (1024, 512) bf16  Wf row-padded
#define SZ_WFB     (1024ull*512*2)
#define OFF_GSUM   (OFF_WFB + SZ_WFB)
#define OFF_GSQ    (OFF_GSUM + 1536*4)
#define OFF_AALL   (OFF_GSQ  + 1536*4)
#define OFF_CALL   (OFF_AALL + 1536*4)
#define OFF_SSUM   (OFF_CALL + 1536*4)
#define OFF_SSQ    (OFF_SSUM + 1024*4)
#define OFF_AF     (OFF_SSQ  + 1024*4)
#define OFF_CF     (OFF_AF   + 1024*4)
#define STATS_ZERO_BYTES (OFF_CF + 1024*4 - OFF_SSUM)

// ---------------- helpers ----------------
__device__ __forceinline__ float bf2f(u16 u) {
  union { unsigned u; float f; } v; v.u = ((unsigned)u) << 16; return v.f;
}
__device__ __forceinline__ u16 f2bf(float f) {   // RNE
  union { float f; unsigned u; } v; v.f = f;
  unsigned r = (v.u + 0x7fffu + ((v.u >> 16) & 1u)) >> 16;
  return (u16)r;
}
__device__ __forceinline__ float sigm(float x) { return 1.f / (1.f + __expf(-x)); }
__device__ __forceinline__ float tanh_(float x) {
  float e = __expf(-2.f * fabsf(x));
  float r = (1.f - e) / (1.f + e);
  return x >= 0.f ? r : -r;
}

// LLC-coherent (device-scope, no-fence) exchange primitives
__device__ __forceinline__ u32 ld4(const u32* p) {
  return __hip_atomic_load(p, __ATOMIC_RELAXED, __HIP_MEMORY_SCOPE_AGENT);
}
__device__ __forceinline__ void st4(u32* p, u32 v) {
  __hip_atomic_store(p, v, __ATOMIC_RELAXED, __HIP_MEMORY_SCOPE_AGENT);
}

// 16B cache-bypassing (LLC-coherent) load, issued without an implicit wait: the
// caller issues a burst of these back-to-back, then one s_waitcnt vmcnt(0).
#define GLD(dst, addr, off) \
  asm volatile("global_load_dwordx4 %0, %1, off offset:" off " sc0 sc1" \
               : "=v"(dst) : "v"(addr))

// 32 loads covering one wave's 32 KB tagged exchange tile: per ks (0..15) two
// dwordx4 at byte offsets ks*128 and ks*128+16 from the per-lane base.
#define BURST32(L, p) do { \
  GLD(L[0],  p, "0");    GLD(L[1],  p, "16");   GLD(L[2],  p, "128");  GLD(L[3],  p, "144");  \
  GLD(L[4],  p, "256");  GLD(L[5],  p, "272");  GLD(L[6],  p, "384");  GLD(L[7],  p, "400");  \
  GLD(L[8],  p, "512");  GLD(L[9],  p, "528");  GLD(L[10], p, "640");  GLD(L[11], p, "656");  \
  GLD(L[12], p, "768");  GLD(L[13], p, "784");  GLD(L[14], p, "896");  GLD(L[15], p, "912");  \
  GLD(L[16], p, "1024"); GLD(L[17], p, "1040"); GLD(L[18], p, "1152"); GLD(L[19], p, "1168"); \
  GLD(L[20], p, "1280"); GLD(L[21], p, "1296"); GLD(L[22], p, "1408"); GLD(L[23], p, "1424"); \
  GLD(L[24], p, "1536"); GLD(L[25], p, "1552"); GLD(L[26], p, "1664"); GLD(L[27], p, "1680"); \
  GLD(L[28], p, "1792"); GLD(L[29], p, "1808"); GLD(L[30], p, "1920"); GLD(L[31], p, "1936"); \
} while (0)

// async global->LDS, 16B/lane
__device__ __forceinline__ void stage16(const u16* g, u16* l) {
  __builtin_amdgcn_global_load_lds((const __attribute__((address_space(1))) unsigned int*)(g),
                                   (__attribute__((address_space(3))) unsigned int*)(l), 16, 0, 0);
}

// ---------------- fp32 -> bf16 converts with padding ----------------
__global__ void cvt_pad(const float* __restrict__ src, u16* __restrict__ dst, int incols, int outcols) {
  int r = blockIdx.x, ci = threadIdx.x;
  float v = (ci < incols) ? src[(size_t)r * incols + ci] : 0.f;
  dst[(size_t)r * outcols + ci] = f2bf(v);
}
__global__ void cvt_wf(const float* __restrict__ src, u16* __restrict__ dst) {
  int r = blockIdx.x, ci = threadIdx.x;     // grid 1024, block 512; rows >= 1000 are zero pad
  float v = (r < 1000) ? src[(size_t)r * 512 + ci] : 0.f;
  dst[(size_t)r * 512 + ci] = f2bf(v);
}

// ---------------- bf16 GEMM  C = A[M,K] @ B[N,K]^T  (128x128 tile, BK=32) ----------------
template<int MODE>
__global__ __launch_bounds__(256, 1) void gemm_bt(const u16* __restrict__ A, const u16* __restrict__ B,
                                                  void* __restrict__ Cout, int K, int ldc, int nlimit) {
  __shared__ __align__(16) u16 smem[16 * 512];
  const int bm = blockIdx.x * 128;
  const int bn = blockIdx.y * 128;
  const int tid = threadIdx.x;
  const int w = tid >> 6;
  const int lane = tid & 63;
  const int r = lane & 15;
  const int q = lane >> 4;
  const int wm = w & 1, wn = w >> 1;

  f32x4 acc[4][4];
#pragma unroll
  for (int i = 0; i < 4; ++i)
#pragma unroll
    for (int j = 0; j < 4; ++j) acc[i][j] = (f32x4){0.f, 0.f, 0.f, 0.f};

  const u16* gA0 = A + (size_t)(bm + w * 16 + r) * K + q * 8;
  const u16* gA1 = A + (size_t)(bm + (w + 4) * 16 + r) * K + q * 8;
  const u16* gB0 = B + (size_t)(bn + w * 16 + r) * K + q * 8;
  const u16* gB1 = B + (size_t)(bn + (w + 4) * 16 + r) * K + q * 8;
  u16* As = smem;
  u16* Bs = smem + 8 * 512;

  for (int k0 = 0; k0 < K; k0 += 32) {
    stage16(gA0 + k0, As + w * 512);
    stage16(gA1 + k0, As + (w + 4) * 512);
    stage16(gB0 + k0, Bs + w * 512);
    stage16(gB1 + k0, Bs + (w + 4) * 512);
    __syncthreads();
    bf16x8 af[4], bf_[4];
#pragma unroll
    for (int mi = 0; mi < 4; ++mi) af[mi] = *(const bf16x8*)(As + (wm * 4 + mi) * 512 + lane * 8);
#pragma unroll
    for (int ni = 0; ni < 4; ++ni) bf_[ni] = *(const bf16x8*)(Bs + (wn * 4 + ni) * 512 + lane * 8);
#pragma unroll
    for (int mi = 0; mi < 4; ++mi)
#pragma unroll
      for (int ni = 0; ni < 4; ++ni)
        acc[mi][ni] = __builtin_amdgcn_mfma_f32_16x16x32_bf16(af[mi], bf_[ni], acc[mi][ni], 0, 0, 0);
    __syncthreads();
  }
  const int row0 = bm + wm * 64;
  const int col0 = bn + wn * 64;
#pragma unroll
  for (int mi = 0; mi < 4; ++mi)
#pragma unroll
    for (int ni = 0; ni < 4; ++ni) {
      int cc = col0 + ni * 16 + r;            // C/D: col=lane&15, row=(lane>>4)*4+reg
      int rr = row0 + mi * 16 + q * 4;
      if (MODE == 1) {
#pragma unroll
        for (int i = 0; i < 4; ++i)
          if (cc < nlimit) ((float*)Cout)[(size_t)(rr + i) * ldc + cc] = acc[mi][ni][i];
      } else {  // transposed bf16: CT[cc][rr..rr+3] as one 8B store
        u64 pk = (u64)f2bf(acc[mi][ni][0]) | ((u64)f2bf(acc[mi][ni][1]) << 16) |
                 ((u64)f2bf(acc[mi][ni][2]) << 32) | ((u64)f2bf(acc[mi][ni][3]) << 48);
        *(u64*)((u16*)Cout + (size_t)cc * ldc + rr) = pk;
      }
    }
}

// ---------------- per-row sum/sumsq over gatesT (1536 rows x 64000) ----------------
__global__ __launch_bounds__(256, 1) void rowstats(const u16* __restrict__ G,
                                                   float* __restrict__ sum, float* __restrict__ sumsq) {
  const int n = blockIdx.x;
  const u16* row = G + (size_t)n * 64000;
  float s = 0.f, ss = 0.f;
  for (int idx = threadIdx.x * 8; idx < 64000; idx += 2048) {
    union { bf16x8 v; u16 e[8]; } u;
    u.v = *(const bf16x8*)(row + idx);
#pragma unroll
    for (int e = 0; e < 8; ++e) { float f = bf2f(u.e[e]); s += f; ss += f * f; }
  }
#pragma unroll
  for (int o = 32; o > 0; o >>= 1) { s += __shfl_xor(s, o); ss += __shfl_xor(ss, o); }
  __shared__ float ls[4], lss[4];
  if ((threadIdx.x & 63) == 0) { ls[threadIdx.x >> 6] = s; lss[threadIdx.x >> 6] = ss; }
  __syncthreads();
  if (threadIdx.x == 0) {
    sum[n]   = ls[0] + ls[1] + ls[2] + ls[3];
    sumsq[n] = lss[0] + lss[1] + lss[2] + lss[3];
  }
}

// ---------------- per-column sum/sumsq over fp32 scores (64000 x 1000) ----------------
__global__ __launch_bounds__(256, 1) void colstats_f32(const float* __restrict__ X, int ld, int ncols,
                                                       float* __restrict__ sum, float* __restrict__ sumsq) {
  const int col = blockIdx.x * 128 + (threadIdx.x & 127);
  const int half = threadIdx.x >> 7;
  const int r0 = blockIdx.y * 2000;
  float s = 0.f, ss = 0.f;
  if (col < ncols) {
    for (int rr = r0 + half; rr < r0 + 2000; rr += 2) {
      float v = X[(size_t)rr * ld + col]; s += v; ss += v * v;
    }
  }
  __shared__ float ls[128], lss[128];
  if (half) { ls[threadIdx.x & 127] = s; lss[threadIdx.x & 127] = ss; }
  __syncthreads();
  if (!half && col < ncols) {
    s += ls[threadIdx.x]; ss += lss[threadIdx.x];
    atomicAdd(&sum[col], s); atomicAdd(&sumsq[col], ss);
  }
}

__global__ void fin_gate(const float* __restrict__ sum, const float* __restrict__ sq,
                         const float* gh, const float* bh, const float* gz, const float* bz,
                         const float* gr, const float* br, float* __restrict__ a, float* __restrict__ c) {
  int j = blockIdx.x * 256 + threadIdx.x;
  if (j >= 1536) return;
  float m = sum[j] * (1.f / 64000.f);
  float v = sq[j] * (1.f / 64000.f) - m * m;
  int seg = j >> 9, jj = j & 511;
  float gg = seg == 0 ? gh[jj] : seg == 1 ? gz[jj] : gr[jj];
  float bb = seg == 0 ? bh[jj] : seg == 1 ? bz[jj] : br[jj];
  float aa = gg * rsqrtf(v + 1e-5f);
  a[j] = aa; c[j] = bb - m * aa;
}

__global__ void fin_score(const float* __restrict__ sum, const float* __restrict__ sq,
                          const float* __restrict__ gfp, const float* __restrict__ bfp,
                          float* __restrict__ a, float* __restrict__ c) {
  int j = blockIdx.x * 256 + threadIdx.x;
  if (j >= 1000) return;
  float m = sum[j] * (1.f / 64000.f);
  float v = sq[j] * (1.f / 64000.f) - m * m;
  float aa = gfp[j] * rsqrtf(v + 1e-5f);
  a[j] = aa; c[j] = bfp[j] - m * aa;
}

// ---------------- persistent GRU scan: sentinel detect + tagged BURST pass ----------------
// Protocol identical to the r3 version (proven: retries ~ 0): atoms are
// u32 = (tag16<<16)|bf16; consumers poll 32 per-producer sentinels (128 B), then do
// ONE full tagged pass and retry only if any tag is stale. The pass is now a burst
// of 32 back-to-back dwordx4 sc0sc1 loads (one address + immediate offsets) with a
// single s_waitcnt — the whole 32 KB tile in ~one LLC round trip instead of the
// VGPR-starved serialized chain the compiler emitted for per-ks 8B loads.
__global__ __launch_bounds__(256, 1) void scan_kernel(
    const u16* __restrict__ gatesT,              // (1536, 64000) bf16 transposed projections (in d_out)
    const float* __restrict__ Uz, const float* __restrict__ Ur, const float* __restrict__ Uh,
    const float* __restrict__ acoef, const float* __restrict__ ccoef,
    u16* __restrict__ hall,                      // (1001*64,512) bf16, write-only here (classifier input)
    u32* __restrict__ hx,                        // [2][64][512] tagged h
    u32* __restrict__ rhx) {                     // [2][64][512] tagged r*h
  __shared__ __align__(16) u16 Us[3][16][520];
  __shared__ float co[6][16];
  const int g = blockIdx.x;
  const int j0 = g * 16;
  const int tid = threadIdx.x;
  const int w = tid >> 6;         // wave -> batch rows [16w,16w+16)
  const int lane = tid & 63;
  const int r = lane & 15;
  const int q = lane >> 4;

  for (int idx = tid; idx < 3 * 16 * 512; idx += 256) {
    int u = idx >> 13;
    int rem = idx & 8191;
    int j = rem >> 9;
    int k = rem & 511;
    const float* U = (u == 0) ? Uz : (u == 1) ? Ur : Uh;
    Us[u][j][k] = f2bf(U[(size_t)(j0 + j) * 512 + k]);
  }
  if (tid < 16) {
    co[0][tid] = acoef[512 + j0 + tid];  co[1][tid] = ccoef[512 + j0 + tid];   // z
    co[2][tid] = acoef[1024 + j0 + tid]; co[3][tid] = ccoef[1024 + j0 + tid];  // r
    co[4][tid] = acoef[j0 + tid];        co[5][tid] = ccoef[j0 + tid];         // h
  }
  __syncthreads();
  const float az = co[0][r], cz = co[1][r], ar = co[2][r], cr = co[3][r];
  const float ah = co[4][r], ch = co[5][r];

  const u16* gRowH = gatesT + (size_t)(j0 + r) * 64000;
  const u16* gRowZ = gatesT + (size_t)(512 + j0 + r) * 64000;
  const u16* gRowR = gatesT + (size_t)(1024 + j0 + r) * 64000;

  const int arow_off = (w * 16 + r) * 512 + q * 8;      // consumer base (u32 units)
  const int prow0 = (w * 16 + q * 4) * 512 + j0 + r;    // producer base (row w*16+q*4, col j0+r)
  const int srow_off = (w * 16 + 15) * 512 + 15;        // sentinel row base + col15

  float hp[4] = {0.f, 0.f, 0.f, 0.f};   // own h slice: rows w*16+q*4+i, col j0+r

  for (int t = 1; t <= S_LEN; ++t) {
    const int ct = (t - 1) * 64 + w * 16 + q * 4;
    const u64 wzq = *(const u64*)(gRowZ + ct);
    const u64 wrq = *(const u64*)(gRowR + ct);
    const u64 whq = *(const u64*)(gRowH + ct);

    // ---- phase A: z, r from h_{t-1}; publish r*h ----
    const u32 tgA = (u32)(t - 1) << 16;
    const u32* hbase = hx + (size_t)((t - 1) & 1) * (64 * 512);
    {
      const u32* sp = hbase + srow_off;        // cheap sentinel detect: 1 atom per producer WG
      for (;;) {
        u32 v = (lane < NWG) ? ld4(sp + lane * 16) : tgA;
        if (__all((v & 0xFFFF0000u) == tgA)) break;
        __builtin_amdgcn_s_sleep(1);
      }
    }
    const u32* hsrc = hbase + arow_off;
    u32x4 L[32];
    for (;;) {
      BURST32(L, hsrc);
      asm volatile("s_waitcnt vmcnt(0)" ::: "memory");
      __builtin_amdgcn_sched_barrier(0);
      u32 bad = 0;
#pragma unroll
      for (int i = 0; i < 32; ++i)
        bad |= (L[i].x ^ tgA) | (L[i].y ^ tgA) | (L[i].z ^ tgA) | (L[i].w ^ tgA);
      if (__all((bad & 0xFFFF0000u) == 0u)) break;   // wave-uniform: MFMA needs all lanes fresh
      __builtin_amdgcn_s_sleep(1);
    }
    f32x4 accz = {0.f, 0.f, 0.f, 0.f}, accr = {0.f, 0.f, 0.f, 0.f};
#pragma unroll
    for (int ks = 0; ks < 16; ++ks) {
      union { u32 p[4]; bf16x8 v; } f;
      u32x4 A0 = L[2 * ks], A1 = L[2 * ks + 1];
      f.p[0] = (A0.x & 0xFFFFu) | (A0.y << 16);
      f.p[1] = (A0.z & 0xFFFFu) | (A0.w << 16);
      f.p[2] = (A1.x & 0xFFFFu) | (A1.y << 16);
      f.p[3] = (A1.z & 0xFFFFu) | (A1.w << 16);
      bf16x8 bz = *(const bf16x8*)(&Us[0][r][ks * 32 + q * 8]);
      bf16x8 br2 = *(const bf16x8*)(&Us[1][r][ks * 32 + q * 8]);
      accz = __builtin_amdgcn_mfma_f32_16x16x32_bf16(f.v, bz, accz, 0, 0, 0);
      accr = __builtin_amdgcn_mfma_f32_16x16x32_bf16(f.v, br2, accr, 0, 0, 0);
    }
    const u32 tgT = (u32)t << 16;
    u32* rdst = rhx + (size_t)(t & 1) * (64 * 512) + prow0;
    float zv[4];
#pragma unroll
    for (int i = 0; i < 4; ++i) {               // r-gate + exchange stores FIRST
      float wr = bf2f((u16)(wrq >> (16 * i)));
      float rv = sigm(accr[i] + wr * ar + cr);
      st4(rdst + i * 512, tgT | (u32)f2bf(rv * hp[i]));
    }
#pragma unroll
    for (int i = 0; i < 4; ++i) {
      float wz = bf2f((u16)(wzq >> (16 * i)));
      zv[i] = sigm(accz[i] + wz * az + cz);
    }

    // ---- phase B: hcand from r*h; publish h_t ----
    const u32* rbase = rhx + (size_t)(t & 1) * (64 * 512);
    {
      const u32* sp = rbase + srow_off;
      for (;;) {
        u32 v = (lane < NWG) ? ld4(sp + lane * 16) : tgT;
        if (__all((v & 0xFFFF0000u) == tgT)) break;
        __builtin_amdgcn_s_sleep(1);
      }
    }
    const u32* rsrc = rbase + arow_off;
    for (;;) {
      BURST32(L, rsrc);
      asm volatile("s_waitcnt vmcnt(0)" ::: "memory");
      __builtin_amdgcn_sched_barrier(0);
      u32 bad = 0;
#pragma unroll
      for (int i = 0; i < 32; ++i)
        bad |= (L[i].x ^ tgT) | (L[i].y ^ tgT) | (L[i].z ^ tgT) | (L[i].w ^ tgT);
      if (__all((bad & 0xFFFF0000u) == 0u)) break;
      __builtin_amdgcn_s_sleep(1);
    }
    f32x4 acch = {0.f, 0.f, 0.f, 0.f};
#pragma unroll
    for (int ks = 0; ks < 16; ++ks) {
      union { u32 p[4]; bf16x8 v; } f;
      u32x4 A0 = L[2 * ks], A1 = L[2 * ks + 1];
      f.p[0] = (A0.x & 0xFFFFu) | (A0.y << 16);
      f.p[1] = (A0.z & 0xFFFFu) | (A0.w << 16);
      f.p[2] = (A1.x & 0xFFFFu) | (A1.y << 16);
      f.p[3] = (A1.z & 0xFFFFu) | (A1.w << 16);
      bf16x8 bh = *(const bf16x8*)(&Us[2][r][ks * 32 + q * 8]);
      acch = __builtin_amdgcn_mfma_f32_16x16x32_bf16(f.v, bh, acch, 0, 0, 0);
    }
    u16* hrow = hall + (size_t)t * (64 * 512);
    u32* hdst = hx + (size_t)(t & 1) * (64 * 512) + prow0;
    u16 hb4[4];
#pragma unroll
    for (int i = 0; i < 4; ++i) {
      float wh = bf2f((u16)(whq >> (16 * i)));
      float hc = tanh_(acch[i] + wh * ah + ch);
      float hn = zv[i] * hp[i] + (1.f - zv[i]) * hc;
      u16 hb = f2bf(hn);
      hb4[i] = hb;
      hp[i] = bf2f(hb);                              // carry own slice (bf16-rounded)
      st4(hdst + i * 512, tgT | (u32)hb);            // exchange store FIRST
    }
#pragma unroll
    for (int i = 0; i < 4; ++i)                      // hall (classifier input) after
      hrow[(size_t)(w * 16 + q * 4 + i) * 512 + j0 + r] = hb4[i];
  }
}

// ---------------- BN + log_softmax, in place on fp32 scores ----------------
__global__ __launch_bounds__(256, 1) void logsoftmax_k(float* __restrict__ S,
                                                       const float* __restrict__ a, const float* __restrict__ c) {
  __shared__ float as_[1000], cs_[1000];
  for (int i = threadIdx.x; i < 1000; i += 256) { as_[i] = a[i]; cs_[i] = c[i]; }
  __syncthreads();
  const int w = threadIdx.x >> 6, lane = threadIdx.x & 63;
  for (int it = 0; it < 4; ++it) {
    const int row = blockIdx.x * 16 + it * 4 + w;
    float* Srow = S + (size_t)row * 1000;
    float tv[16];
    float mx = -3.0e38f;
#pragma unroll
    for (int qq = 0; qq < 16; ++qq) {
      int j = lane + qq * 64;
      float v = -3.0e38f;
      if (j < 1000) v = as_[j] * Srow[j] + cs_[j];
      tv[qq] = v;
      mx = fmaxf(mx, v);
    }
#pragma unroll
    for (int o = 32; o > 0; o >>= 1) mx = fmaxf(mx, __shfl_xor(mx, o));
    float sm = 0.f;
#pragma unroll
    for (int qq = 0; qq < 16; ++qq) sm += __expf(tv[qq] - mx);
#pragma unroll
    for (int o = 32; o > 0; o >>= 1) sm += __shfl_xor(sm, o);
    float lse = mx + __logf(sm);
#pragma unroll
    for (int qq = 0; qq < 16; ++qq) {
      int j = lane + qq * 64;
      if (j < 1000) Srow[j] = tv[qq] - lse;
    }
  }
}

// ---------------- launch ----------------
extern "C" void kernel_launch(void* const* d_in, const int* in_sizes, int n_in,
                              void* d_out, int out_size, void* d_ws, size_t ws_size,
                              hipStream_t stream) {
  const float* x  = (const float*)d_in[0];
  const float* Wh = (const float*)d_in[1];
  const float* Wz = (const float*)d_in[2];
  const float* Wr = (const float*)d_in[3];
  const float* Uh = (const float*)d_in[4];
  const float* Uz = (const float*)d_in[5];
  const float* Ur = (const float*)d_in[6];
  const float* gh = (const float*)d_in[7];
  const float* bh = (const float*)d_in[8];
  const float* gz = (const float*)d_in[9];
  const float* bz = (const float*)d_in[10];
  const float* gr = (const float*)d_in[11];
  const float* br = (const float*)d_in[12];
  const float* Wf = (const float*)d_in[13];
  const float* gf = (const float*)d_in[14];
  const float* bfp = (const float*)d_in[15];

  uint8_t* ws = (uint8_t*)d_ws;
  u16* hall = (u16*)(ws + OFF_HALL);
  u16* xb   = (u16*)(ws + OFF_HALL);   // alias: xb dead before hall is written
  u16* wcat = (u16*)(ws + OFF_WCAT);
  u16* wfb  = (u16*)(ws + OFF_WFB);
  u32* hx   = (u32*)(ws + OFF_HX);     // aliases wcat (dead after proj GEMM)
  u32* rhx  = (u32*)(ws + OFF_RHX);    // aliases wcat
  float* gsum = (float*)(ws + OFF_GSUM);
  float* gsq  = (float*)(ws + OFF_GSQ);
  float* aall = (float*)(ws + OFF_AALL);
  float* call = (float*)(ws + OFF_CALL);
  float* ssum = (float*)(ws + OFF_SSUM);
  float* ssq  = (float*)(ws + OFF_SSQ);
  float* af   = (float*)(ws + OFF_AF);
  float* cf   = (float*)(ws + OFF_CF);

  u16* gatesT = (u16*)d_out;     // (1536, 64000) bf16, dead after scan
  float* scores = (float*)d_out; // (64000,1000) fp32, written by classifier GEMM

  hipMemsetAsync(ws + OFF_SSUM, 0, (size_t)STATS_ZERO_BYTES, stream);

  cvt_pad<<<dim3(64000), dim3(448), 0, stream>>>(x, xb, 440, 448);
  cvt_pad<<<dim3(512), dim3(448), 0, stream>>>(Wh, wcat, 440, 448);
  cvt_pad<<<dim3(512), dim3(448), 0, stream>>>(Wz, wcat + 512 * 448, 440, 448);
  cvt_pad<<<dim3(512), dim3(448), 0, stream>>>(Wr, wcat + 1024 * 448, 440, 448);
  cvt_wf<<<dim3(1024), dim3(512), 0, stream>>>(Wf, wfb);

  gemm_bt<2><<<dim3(500, 12), dim3(256), 0, stream>>>(xb, wcat, (void*)gatesT, 448, 64000, 1536);

  rowstats<<<dim3(1536), dim3(256), 0, stream>>>(gatesT, gsum, gsq);
  fin_gate<<<dim3(6), dim3(256), 0, stream>>>(gsum, gsq, gh, bh, gz, bz, gr, br, aall, call);

  // wcat is dead from here on: zero the aliased tagged exchange buffers
  // (tag0|val0 == valid h_0 = 0; clears stale tags from any previous launch)
  hipMemsetAsync(ws + OFF_HX, 0, (size_t)(SZ_HX + SZ_RHX), stream);

  scan_kernel<<<dim3(NWG), dim3(256), 0, stream>>>(gatesT, Uz, Ur, Uh, aall, call, hall, hx, rhx);

  gemm_bt<1><<<dim3(500, 8), dim3(256), 0, stream>>>(hall + 64 * 512, wfb, (void*)scores, 512, 1000, 1000);

  colstats_f32<<<dim3(8, 32), dim3(256), 0, stream>>>(scores, 1000, 1000, ssum, ssq);
  fin_score<<<dim3(4), dim3(256), 0, stream>>>(ssum, ssq, gf, bfp, af, cf);

  logsoftmax_k<<<dim3(4000), dim3(256), 0, stream>>>(scores, af, cf);
}